// Round 3
// baseline (136.249 us; speedup 1.0000x reference)
//
#include <hip/hip_runtime.h>

// Problem constants (from reference): input [8,16,512,1024] f32, disp [8,1,512,1024] f32
constexpr int B = 8;
constexpr int C = 16;
constexpr int H = 512;
constexpr int W = 1024;

// One thread per (b,h,w) position. Horizontal bilinear warp:
//   x  = clip(w + disp, 0, W-1)
//   x0 = floor(x); x1 = min(x0+1, W-1)
//   wl = x1 - x;  wr = x - x0        (both 0 when x hits the right clamp)
// Weights/indices computed once, reused across all C channels.
__global__ __launch_bounds__(256) void warp_bilinear_w(
    const float* __restrict__ input,
    const float* __restrict__ disp,
    float* __restrict__ out)
{
    const int idx = blockIdx.x * blockDim.x + threadIdx.x;   // over B*H*W
    if (idx >= B * H * W) return;

    const int w  = idx & (W - 1);        // W = 1024 = 2^10
    const int bh = idx >> 10;            // b*H + h
    const int b  = bh >> 9;              // H = 512 = 2^9
    const int h  = bh & (H - 1);

    const float d = disp[idx];           // disp is [B,1,H,W] -> flat == idx
    float x = (float)w + d;
    x = fminf(fmaxf(x, 0.0f), (float)(W - 1));
    const float x0f = floorf(x);
    const float x1f = fminf(x0f + 1.0f, (float)(W - 1));
    const int   x0  = (int)x0f;
    const int   x1  = (int)x1f;
    const float wl  = x1f - x;
    const float wr  = x - x0f;

    // base index of (b, c=0, h, :) in input/out; channel stride = H*W
    const int base = (b * C * H + h) * W;

#pragma unroll
    for (int c = 0; c < C; ++c) {
        const int rowoff = base + c * (H * W);
        const float pl = input[rowoff + x0];
        const float pr = input[rowoff + x1];
        out[rowoff + w] = wl * pl + wr * pr;
    }
}

extern "C" void kernel_launch(void* const* d_in, const int* in_sizes, int n_in,
                              void* d_out, int out_size, void* d_ws, size_t ws_size,
                              hipStream_t stream) {
    const float* input = (const float*)d_in[0];
    const float* disp  = (const float*)d_in[1];
    float* out = (float*)d_out;

    const int n = B * H * W;                 // 4,194,304 positions
    const int block = 256;
    const int grid = (n + block - 1) / block;  // 16384 blocks
    warp_bilinear_w<<<grid, block, 0, stream>>>(input, disp, out);
}